// Round 1
// 2578.206 us; speedup vs baseline: 2.4947x; 2.4947x over previous
//
#include <hip/hip_runtime.h>
#include <stdint.h>

#define NBATCH 32
#define NPTS   65536
#define MCENT  2048
#define BPB    8                 // blocks per batch
#define THREADS 1024
#define CHUNK  (NPTS / BPB)      // 8192 points per block
#define WPT    (CHUNK / THREADS) // 8 points per thread
#define NWAVE  (THREADS / 64)    // 16 waves
#define EPB    8                 // published words per block: 4 quads x top-2
#define EPBATCH (BPB * EPB)      // 64 words per batch per parity
#define TMAX   16                // max centers selected per sync round

typedef unsigned long long u64;
typedef uint32_t u32;

static __device__ __forceinline__ u32 fbits(float f) { union { float f; u32 u; } c; c.f = f; return c.u; }
static __device__ __forceinline__ float bitsf(u32 u) { union { u32 u; float f; } c; c.u = u; return c.f; }

// Multi-step FPS: one all-to-all sync amortizes over several exact FPS steps.
//
// Pool protocol (d_ws, 32 KiB = 2 parity x 32 batch x 64 u64 words):
//   each block publishes top-2 keys per quad (quad = 4 waves = 2048 pts).
//   word = val_bits[63:32] | (idx^0xFFFF)[31:16] | sync_tag[15:0]
//   key  = word >> 16  -> single u64 compare == (max val, then min idx),
//   matching jnp.argmax first-occurrence tie-breaking exactly.
//   Tags: poison 0xAA.. -> 0xAAAA, zero -> 0; s in [1,2047] never aliases.
//   Parity reuse safe: a block overwrites parity-p words at round s+2 only
//   after observing all round-s+1 tags, which requires every peer to have
//   finished its round-s reads (values banked in registers by the poll).
//
// Exactness of pool-FPS steps (all blocks replicate identically):
//   step 1: pool contains every quad's max -> pool argmax == global argmax.
//   step t>=2: any point NOT in the pool is bounded by its quad's published
//   2nd value <= tau = max over quads of 2nd values. Accept winner iff its
//   VALUE strictly > tau (hidden points can then neither beat nor tie it);
//   otherwise bail, re-update full arrays vs the t winners, re-sync.
//   Distance math is the verified bit-exact chain: subs, then
//   fma(dz,dz, fma(dx,dx, mul(dy,dy))), chronological fminf order.

__global__ __launch_bounds__(THREADS, 1) void fps_kernel(
    const float* __restrict__ xyz,      // [NBATCH, NPTS, 3] fp32
    float* __restrict__ out,            // [NBATCH, MCENT, 3] fp32
    u64* __restrict__ slots)            // needs 32 KiB
{
    const int t = threadIdx.x;
    const int b = blockIdx.x >> 3;   // batch
    const int j = blockIdx.x & 7;    // block-within-batch
    const float* base = xyz + (size_t)b * NPTS * 3;
    const int p0 = j * CHUNK;
    const int wave = t >> 6;
    const int lane = t & 63;

    // coords + running min-dist live in registers
    float px[WPT], py[WPT], pz[WPT], pd[WPT];
#pragma unroll
    for (int q = 0; q < WPT; ++q) {
        const int p = p0 + q * THREADS + t;
        px[q] = base[(size_t)p * 3 + 0];
        py[q] = base[(size_t)p * 3 + 1];
        pz[q] = base[(size_t)p * 3 + 2];
        pd[q] = 1e10f;
    }

    __shared__ float wcx[TMAX], wcy[TMAX], wcz[TMAX]; // winners of last round
    __shared__ int   wcnt;
    __shared__ u64   wavecand[NWAVE * 2];             // per-wave top-2 keys

    if (t == 0) {
        const float cx = base[0], cy = base[1], cz = base[2];
        wcx[0] = cx; wcy[0] = cy; wcz[0] = cz; wcnt = 1;
        if (j == 0) {
            float* o = out + (size_t)b * MCENT * 3;
            o[0] = cx; o[1] = cy; o[2] = cz;
        }
    }

    int C = 0;  // centers accounted (uniform across all blocks)
    for (int s = 1; ; ++s) {
        __syncthreads();                 // wcnt / wc* of previous round valid
        const int tn = wcnt;
        C += tn;
        if (C >= MCENT) break;

        // ---- Phase A: update running min-dist vs the tn new centers ----
        for (int tt = 0; tt < tn; ++tt) {
            const float cx = wcx[tt], cy = wcy[tt], cz = wcz[tt];
#pragma unroll
            for (int q = 0; q < WPT; ++q) {
                const float dx = __fsub_rn(px[q], cx);
                const float dy = __fsub_rn(py[q], cy);
                const float dz = __fsub_rn(pz[q], cz);
                const float s2 = __fmaf_rn(dz, dz,
                                 __fmaf_rn(dx, dx,
                                 __fmul_rn(dy, dy)));
                pd[q] = fminf(pd[q], s2);
            }
        }

        // ---- per-lane top-2 keys over its 8 points ----
        u64 k1 = 0, k2 = 0;
#pragma unroll
        for (int q = 0; q < WPT; ++q) {
            const u64 kk = ((u64)fbits(pd[q]) << 16)
                         | (u64)(0xFFFFu ^ (u32)(p0 + q * THREADS + t));
            if (kk > k1) { k2 = k1; k1 = kk; } else if (kk > k2) { k2 = kk; }
        }
        // ---- wave top-2 butterfly (all lanes converge) ----
#pragma unroll
        for (int m = 1; m <= 32; m <<= 1) {
            const u64 o1 = __shfl_xor(k1, m);
            const u64 o2 = __shfl_xor(k2, m);
            if (o1 > k1) { k2 = (k1 > o2) ? k1 : o2; k1 = o1; }
            else         { k2 = (k2 > o1) ? k2 : o1; }
        }
        if (lane == 0) { wavecand[wave * 2] = k1; wavecand[wave * 2 + 1] = k2; }
        __syncthreads();

        if (wave == 0) {
            u64* const bb = slots + ((size_t)(s & 1) * NBATCH + b) * EPBATCH;
            const u32 tag = (u32)s & 0xFFFFu;

            // ---- quad merge (lane q<4 owns waves 4q..4q+3) + publish ----
            if (lane < 4) {
                u64 m1 = 0, m2 = 0;
#pragma unroll
                for (int i = 0; i < 8; ++i) {
                    const u64 c = wavecand[lane * 8 + i];
                    if (c > m1) { m2 = m1; m1 = c; } else if (c > m2) { m2 = c; }
                }
                __hip_atomic_store(&bb[j * EPB + lane * 2 + 0], (m1 << 16) | tag,
                                   __ATOMIC_RELAXED, __HIP_MEMORY_SCOPE_AGENT);
                __hip_atomic_store(&bb[j * EPB + lane * 2 + 1], (m2 << 16) | tag,
                                   __ATOMIC_RELAXED, __HIP_MEMORY_SCOPE_AGENT);
            }

            // ---- poll: 1 word per lane until all 64 carry tag s ----
            u64 w; int ok;
            do {
                w = __hip_atomic_load(&bb[lane], __ATOMIC_RELAXED,
                                      __HIP_MEMORY_SCOPE_AGENT);
                ok = ((u32)(w & 0xFFFFull) == tag);
            } while (!__all(ok));

            // ---- unpack entry + gather its coords (xyz is read-only) ----
            u64 pk = w >> 16;                         // live key: val|invidx
            const int pidx = (int)(0xFFFFu ^ (u32)(pk & 0xFFFFull));
            const float ex = base[(size_t)pidx * 3 + 0];
            const float ey = base[(size_t)pidx * 3 + 1];
            const float ez = base[(size_t)pidx * 3 + 2];

            // tau = max over quad-SECOND entries (odd word index) of value
            u32 tauv = (lane & 1) ? (u32)(pk >> 16) : 0u;
#pragma unroll
            for (int m = 1; m <= 32; m <<= 1) {
                const u32 o = __shfl_xor(tauv, m);
                tauv = (o > tauv) ? o : tauv;
            }

            // ---- pool-FPS: exact multi-step selection ----
            int tc = 0;
            while (1) {
                u64 mx = pk;
#pragma unroll
                for (int m = 1; m <= 32; m <<= 1) {
                    const u64 o = __shfl_xor(mx, m);
                    if (o > mx) mx = o;
                }
                // step >=2 valid only if winner VALUE strictly beats tau
                if (tc > 0 && (u32)(mx >> 16) <= tauv) break;

                const u64 bal = __ballot(pk == mx);   // unique owner (idx unique)
                const int ol = (int)__ffsll((long long)bal) - 1;
                const float wx = __shfl(ex, ol);
                const float wy = __shfl(ey, ol);
                const float wz = __shfl(ez, ol);
                if (lane == 0) {
                    wcx[tc] = wx; wcy[tc] = wy; wcz[tc] = wz;
                    if (j == 0) {
                        float* o = out + ((size_t)b * MCENT + (C + tc)) * 3;
                        o[0] = wx; o[1] = wy; o[2] = wz;
                    }
                }
                ++tc;
                if (C + tc >= MCENT || tc >= TMAX) break;

                // min-update pool entries vs winner (bit-exact chain);
                // winner's own entry sinks to 0 automatically
                const float dx = __fsub_rn(ex, wx);
                const float dy = __fsub_rn(ey, wy);
                const float dz = __fsub_rn(ez, wz);
                const float s2 = __fmaf_rn(dz, dz,
                                 __fmaf_rn(dx, dx,
                                 __fmul_rn(dy, dy)));
                const float nv = fminf(bitsf((u32)(pk >> 16)), s2);
                pk = ((u64)fbits(nv) << 16) | (pk & 0xFFFFull);
            }
            if (lane == 0) wcnt = tc;
        }
        // waves 1..15 fall through to the loop-top barrier while wave 0
        // finishes the pool; wavecand is not rewritten until after it.
    }
}

extern "C" void kernel_launch(void* const* d_in, const int* in_sizes, int n_in,
                              void* d_out, int out_size, void* d_ws, size_t ws_size,
                              hipStream_t stream) {
    const float* xyz = (const float*)d_in[0];
    float* out = (float*)d_out;
    u64* slots = (u64*)d_ws; // needs 32 KiB

    fps_kernel<<<dim3(NBATCH * BPB), dim3(THREADS), 0, stream>>>(xyz, out, slots);
}

// Round 2
// 2326.544 us; speedup vs baseline: 2.7646x; 1.1082x over previous
//
#include <hip/hip_runtime.h>
#include <stdint.h>

#define NBATCH 32
#define NPTS   65536
#define MCENT  2048
#define BPB    8                 // blocks per batch
#define THREADS 1024
#define CHUNK  (NPTS / BPB)      // 8192 points per block
#define WPT    (CHUNK / THREADS) // 8 points per thread
#define NWAVE  (THREADS / 64)    // 16 waves
#define EPW    2                 // published words per wave (top-2)
#define POOLW  (BPB * NWAVE * EPW) // 256 words per batch per parity
#define WPL    (POOLW / 64)      // 4 words per lane in wave 0
#define TMAX   32                // max centers selected per sync round

typedef unsigned long long u64;
typedef uint32_t u32;

static __device__ __forceinline__ u32 fbits(float f) { union { float f; u32 u; } c; c.f = f; return c.u; }
static __device__ __forceinline__ float bitsf(u32 u) { union { u32 u; float f; } c; c.u = u; return c.f; }

// Multi-step FPS, per-WAVE candidate pool (finer groups -> higher tau bound).
//
// Pool protocol (d_ws, 128 KiB = 2 parity x 32 batch x 256 u64 words):
//   each WAVE publishes its exact top-2 keys (512-point groups).
//   word = val_bits[63:32] | (idx^0xFFFF)[31:16] | sync_tag[15:0]
//   key  = word >> 16 -> one u64 compare == (max val, then min idx),
//   matching jnp.argmax first-occurrence tie-breaking exactly.
//   Tags: poison 0xAA.. -> 0xAAAA, zero -> 0; s in [1,2047] never aliases.
//   Parity reuse safe: a block overwrites parity-p words at round s+2 only
//   after observing all round-s+1 tags; a peer publishes s+1 only after its
//   round-s poll banked all round-s words in registers. Publishing a word
//   whose value depends on this round's LDS/Phase-A reads also orders those
//   reads by dataflow, so wave 0 may overwrite the winner LDS safely.
//
// Exactness (all blocks replicate the identical pool computation):
//   step 1: pool contains every wave-group's max -> pool argmax == global
//   argmax (ties resolve by key packing, first occurrence).
//   step t>=2: any point NOT in the pool is <= its wave's published 2nd
//   <= tau = max over waves of 2nd values (static bound; true distances
//   only decrease). Accept a winner iff its VALUE strictly > tau; else
//   bail, re-run Phase A vs this round's winners, re-publish, re-sync.
//   Distance math everywhere is the verified bit-exact chain: subs, then
//   fma(dz,dz, fma(dx,dx, mul(dy,dy))), chronological fminf order.

__global__ __launch_bounds__(THREADS, 1) void fps_kernel(
    const float* __restrict__ xyz,      // [NBATCH, NPTS, 3] fp32
    float* __restrict__ out,            // [NBATCH, MCENT, 3] fp32
    u64* __restrict__ slots)            // needs 128 KiB
{
    const int t = threadIdx.x;
    const int b = blockIdx.x >> 3;   // batch
    const int j = blockIdx.x & 7;    // block-within-batch
    const float* base = xyz + (size_t)b * NPTS * 3;
    const int p0 = j * CHUNK;
    const int wave = t >> 6;
    const int lane = t & 63;

    // coords + running min-dist live in registers
    float px[WPT], py[WPT], pz[WPT], pd[WPT];
#pragma unroll
    for (int q = 0; q < WPT; ++q) {
        const int p = p0 + q * THREADS + t;
        px[q] = base[(size_t)p * 3 + 0];
        py[q] = base[(size_t)p * 3 + 1];
        pz[q] = base[(size_t)p * 3 + 2];
        pd[q] = 1e10f;
    }

    __shared__ float wcx[TMAX], wcy[TMAX], wcz[TMAX]; // winners of last round
    __shared__ int   wcnt;

    if (t == 0) {
        const float cx = base[0], cy = base[1], cz = base[2];
        wcx[0] = cx; wcy[0] = cy; wcz[0] = cz; wcnt = 1;
        if (j == 0) {
            float* o = out + (size_t)b * MCENT * 3;
            o[0] = cx; o[1] = cy; o[2] = cz;
        }
    }

    int C = 0;  // centers accounted (uniform across all blocks)
    for (int s = 1; ; ++s) {
        __syncthreads();                 // wcnt / wc* of previous round valid
        const int tn = wcnt;
        C += tn;
        if (C >= MCENT) break;

        // ---- Phase A: update running min-dist vs the tn new centers ----
        for (int tt = 0; tt < tn; ++tt) {
            const float cx = wcx[tt], cy = wcy[tt], cz = wcz[tt];
#pragma unroll
            for (int q = 0; q < WPT; ++q) {
                const float dx = __fsub_rn(px[q], cx);
                const float dy = __fsub_rn(py[q], cy);
                const float dz = __fsub_rn(pz[q], cz);
                const float s2 = __fmaf_rn(dz, dz,
                                 __fmaf_rn(dx, dx,
                                 __fmul_rn(dy, dy)));
                pd[q] = fminf(pd[q], s2);
            }
        }

        // ---- per-lane top-2 keys over its 8 points ----
        u64 k1 = 0, k2 = 0;
#pragma unroll
        for (int q = 0; q < WPT; ++q) {
            const u64 kk = ((u64)fbits(pd[q]) << 16)
                         | (u64)(0xFFFFu ^ (u32)(p0 + q * THREADS + t));
            if (kk > k1) { k2 = k1; k1 = kk; } else if (kk > k2) { k2 = kk; }
        }
        // ---- wave top-2 butterfly (all lanes converge; exact wave top-2) ----
#pragma unroll
        for (int m = 1; m <= 32; m <<= 1) {
            const u64 o1 = __shfl_xor(k1, m);
            const u64 o2 = __shfl_xor(k2, m);
            if (o1 > k1) { k2 = (k1 > o2) ? k1 : o2; k1 = o1; }
            else         { k2 = (k2 > o1) ? k2 : o1; }
        }

        u64* const bb = slots + ((size_t)(s & 1) * NBATCH + b) * POOLW;
        const u32 tag = (u32)s & 0xFFFFu;

        // ---- publish: each wave's lane 0 stores its 2 tagged words ----
        if (lane == 0) {
            __hip_atomic_store(&bb[j * (NWAVE * EPW) + wave * EPW + 0],
                               (k1 << 16) | tag,
                               __ATOMIC_RELAXED, __HIP_MEMORY_SCOPE_AGENT);
            __hip_atomic_store(&bb[j * (NWAVE * EPW) + wave * EPW + 1],
                               (k2 << 16) | tag,
                               __ATOMIC_RELAXED, __HIP_MEMORY_SCOPE_AGENT);
        }
        // waves 1..15 fall through to the loop-top barrier; wave 0 polls.

        if (wave == 0) {
            // ---- poll: 4 coalesced words per lane until all carry tag s ----
            u64 w0, w1, w2, w3; int ok;
            do {
                w0 = __hip_atomic_load(&bb[lane +   0], __ATOMIC_RELAXED, __HIP_MEMORY_SCOPE_AGENT);
                w1 = __hip_atomic_load(&bb[lane +  64], __ATOMIC_RELAXED, __HIP_MEMORY_SCOPE_AGENT);
                w2 = __hip_atomic_load(&bb[lane + 128], __ATOMIC_RELAXED, __HIP_MEMORY_SCOPE_AGENT);
                w3 = __hip_atomic_load(&bb[lane + 192], __ATOMIC_RELAXED, __HIP_MEMORY_SCOPE_AGENT);
                ok = ((u32)(w0 & 0xFFFFull) == tag) &
                     ((u32)(w1 & 0xFFFFull) == tag) &
                     ((u32)(w2 & 0xFFFFull) == tag) &
                     ((u32)(w3 & 0xFFFFull) == tag);
            } while (!__all(ok));

            // ---- unpack 4 pool entries + gather coords (xyz read-only) ----
            u64 pk0 = w0 >> 16, pk1 = w1 >> 16, pk2 = w2 >> 16, pk3 = w3 >> 16;
            const int i0 = 0xFFFF ^ (int)(pk0 & 0xFFFFull);
            const int i1 = 0xFFFF ^ (int)(pk1 & 0xFFFFull);
            const int i2 = 0xFFFF ^ (int)(pk2 & 0xFFFFull);
            const int i3 = 0xFFFF ^ (int)(pk3 & 0xFFFFull);
            const float ex0 = base[(size_t)i0 * 3 + 0], ey0 = base[(size_t)i0 * 3 + 1], ez0 = base[(size_t)i0 * 3 + 2];
            const float ex1 = base[(size_t)i1 * 3 + 0], ey1 = base[(size_t)i1 * 3 + 1], ez1 = base[(size_t)i1 * 3 + 2];
            const float ex2 = base[(size_t)i2 * 3 + 0], ey2 = base[(size_t)i2 * 3 + 1], ez2 = base[(size_t)i2 * 3 + 2];
            const float ex3 = base[(size_t)i3 * 3 + 0], ey3 = base[(size_t)i3 * 3 + 1], ez3 = base[(size_t)i3 * 3 + 2];

            // tau = max over wave-SECOND entries of value.
            // word index = lane + 64*r, so (index&1)==(lane&1): odd lanes
            // hold exactly the second-entry words.
            u32 tauv = 0;
            if (lane & 1) {
                const u32 v0 = (u32)(pk0 >> 16), v1 = (u32)(pk1 >> 16);
                const u32 v2 = (u32)(pk2 >> 16), v3 = (u32)(pk3 >> 16);
                u32 m01 = v0 > v1 ? v0 : v1;
                u32 m23 = v2 > v3 ? v2 : v3;
                tauv = m01 > m23 ? m01 : m23;
            }
#pragma unroll
            for (int m = 1; m <= 32; m <<= 1) {
                const u32 o = __shfl_xor(tauv, m);
                tauv = (o > tauv) ? o : tauv;
            }

            // ---- pool-FPS: exact multi-step selection ----
            int tc = 0;
            while (1) {
                // local max over 4 entries, tracking its coords
                u64 mxl = pk0; float sx = ex0, sy = ey0, sz = ez0;
                if (pk1 > mxl) { mxl = pk1; sx = ex1; sy = ey1; sz = ez1; }
                if (pk2 > mxl) { mxl = pk2; sx = ex2; sy = ey2; sz = ez2; }
                if (pk3 > mxl) { mxl = pk3; sx = ex3; sy = ey3; sz = ez3; }
                u64 mx = mxl;
#pragma unroll
                for (int m = 1; m <= 32; m <<= 1) {
                    const u64 o = __shfl_xor(mx, m);
                    if (o > mx) mx = o;
                }
                // step >=2 valid only if winner VALUE strictly beats tau
                if (tc > 0 && (u32)(mx >> 16) <= tauv) break;

                const u64 bal = __ballot(mxl == mx);  // unique (idx unique)
                const int ol = (int)__ffsll((long long)bal) - 1;
                const float wx = __shfl(sx, ol);
                const float wy = __shfl(sy, ol);
                const float wz = __shfl(sz, ol);
                if (lane == 0) {
                    wcx[tc] = wx; wcy[tc] = wy; wcz[tc] = wz;
                    if (j == 0) {
                        float* o = out + ((size_t)b * MCENT + (C + tc)) * 3;
                        o[0] = wx; o[1] = wy; o[2] = wz;
                    }
                }
                ++tc;
                if (C + tc >= MCENT || tc >= TMAX) break;

                // min-update all 4 entries vs winner (bit-exact chain);
                // winner's own entry sinks to 0 automatically
#define UPD(PK, AX, AY, AZ) { \
                const float dx = __fsub_rn(AX, wx); \
                const float dy = __fsub_rn(AY, wy); \
                const float dz = __fsub_rn(AZ, wz); \
                const float s2 = __fmaf_rn(dz, dz, \
                                 __fmaf_rn(dx, dx, \
                                 __fmul_rn(dy, dy))); \
                const float nv = fminf(bitsf((u32)(PK >> 16)), s2); \
                PK = ((u64)fbits(nv) << 16) | (PK & 0xFFFFull); }
                UPD(pk0, ex0, ey0, ez0)
                UPD(pk1, ex1, ey1, ez1)
                UPD(pk2, ex2, ey2, ez2)
                UPD(pk3, ex3, ey3, ez3)
#undef UPD
            }
            if (lane == 0) wcnt = tc;
        }
    }
}

extern "C" void kernel_launch(void* const* d_in, const int* in_sizes, int n_in,
                              void* d_out, int out_size, void* d_ws, size_t ws_size,
                              hipStream_t stream) {
    const float* xyz = (const float*)d_in[0];
    float* out = (float*)d_out;
    u64* slots = (u64*)d_ws; // needs 128 KiB

    fps_kernel<<<dim3(NBATCH * BPB), dim3(THREADS), 0, stream>>>(xyz, out, slots);
}

// Round 4
// 2089.992 us; speedup vs baseline: 3.0775x; 1.1132x over previous
//
#include <hip/hip_runtime.h>
#include <stdint.h>

#define NBATCH 32
#define NPTS   65536
#define MCENT  2048
#define BPB    8                 // blocks per batch
#define THREADS 1024
#define CHUNK  (NPTS / BPB)      // 8192 points per block
#define WPT    (CHUNK / THREADS) // 8 points per thread
#define NWAVE  (THREADS / 64)    // 16 waves
#define TMAX   64                // max centers selected per sync round

typedef unsigned long long u64;
typedef uint32_t u32;

static __device__ __forceinline__ u32 fbits(float f) { union { float f; u32 u; } c; c.f = f; return c.u; }
static __device__ __forceinline__ float bitsf(u32 u) { union { u32 u; float f; } c; c.u = u; return c.f; }

// wave-wide max of nonneg u32 via DPP row reduce (rocPRIM idiom, CDNA-valid);
// bound_ctrl=true -> invalid/OOB sources read 0 (identity for nonneg max).
// Result uniform via readlane 63.
static __device__ __forceinline__ u32 wave_max_u32(u32 v) {
#define STEP(CTRL) { const u32 o = (u32)__builtin_amdgcn_update_dpp(0, (int)v, CTRL, 0xF, 0xF, true); v = o > v ? o : v; }
    STEP(0x111) // row_shr:1
    STEP(0x112) // row_shr:2
    STEP(0x114) // row_shr:4
    STEP(0x118) // row_shr:8   -> lane 15+16k holds its row's max
    STEP(0x142) // row_bcast15 -> lane 31 = rows0|1, lane 63 += row2
    STEP(0x143) // row_bcast31 -> lane 63 = full-wave max
#undef STEP
    return (u32)__builtin_amdgcn_readlane((int)v, 63);
}

// Multi-step FPS with a published candidate pool; one all-to-all sync
// amortizes over several exact FPS steps.
//
// GPW = groups per wave. GPW=1: top-2 per wave (proven R2 protocol,
// 128 KiB ws). GPW=2: top-2 per half-wave (finer groups -> lower tau ->
// more steps/sync; 256 KiB ws). Host gates on ws_size.
//
// Pool protocol (d_ws = 2 parity x NBATCH x POOLW u64 words):
//   word = val_bits[63:32] | (idx^0xFFFF)[31:16] | sync_tag[15:0]
//   key order (val desc, idx asc) == jnp.argmax first-occurrence semantics.
//   Tags: poison 0xAA.. -> 0xAAAA, zero -> 0; s in [1,2047] never aliases.
//   Parity reuse safe: a block overwrites parity-p words at round s+2 only
//   after observing all round-s+1 tags; a peer publishes s+1 only after its
//   round-s poll banked all round-s words in registers.
//
// Exactness (every block replicates the identical pool computation):
//   step 1: pool holds every group's max -> pool argmax == global argmax.
//   step t>=2: any point NOT in the pool is <= its group's published 2nd
//   <= tau = max over groups of 2nd values (true dists only decrease).
//   Accept a winner iff its VALUE strictly > tau (hidden points can then
//   neither beat nor tie it); else bail, re-run Phase A, re-publish.
//   All distance math is the verified bit-exact chain: subs, then
//   fma(dz,dz, fma(dx,dx, mul(dy,dy))), chronological fminf order.

template<int GPW>
__global__ __launch_bounds__(THREADS, 1) void fps_kernel(
    const float* __restrict__ xyz,      // [NBATCH, NPTS, 3] fp32
    float* __restrict__ out,            // [NBATCH, MCENT, 3] fp32
    u64* __restrict__ slots)
{
    constexpr int GROUPL = 64 / GPW;               // lanes per group
    constexpr int POOLW  = BPB * NWAVE * GPW * 2;  // words per batch per parity
    constexpr int WPL    = POOLW / 64;             // words per lane (wave 0)

    const int t = threadIdx.x;
    const int b = blockIdx.x >> 3;   // batch (proven mapping)
    const int j = blockIdx.x & 7;    // block-within-batch
    const float* base = xyz + (size_t)b * NPTS * 3;
    const int p0 = j * CHUNK;
    const int wave = t >> 6;
    const int lane = t & 63;

    // coords + running min-dist live in registers
    float px[WPT], py[WPT], pz[WPT], pd[WPT];
#pragma unroll
    for (int q = 0; q < WPT; ++q) {
        const int p = p0 + q * THREADS + t;
        px[q] = base[(size_t)p * 3 + 0];
        py[q] = base[(size_t)p * 3 + 1];
        pz[q] = base[(size_t)p * 3 + 2];
        pd[q] = 1e10f;
    }

    __shared__ float wcx[TMAX], wcy[TMAX], wcz[TMAX]; // winners of last round
    __shared__ int   wcnt;

    if (t == 0) {
        const float cx = base[0], cy = base[1], cz = base[2];
        wcx[0] = cx; wcy[0] = cy; wcz[0] = cz; wcnt = 1;
        if (j == 0) {
            float* o = out + (size_t)b * MCENT * 3;
            o[0] = cx; o[1] = cy; o[2] = cz;
        }
    }

    int C = 0;  // centers accounted (uniform across all blocks)
    for (int s = 1; ; ++s) {
        __syncthreads();                 // wcnt / wc* of previous round valid
        const int tn = wcnt;
        C += tn;
        if (C >= MCENT) break;

        // ---- Phase A: update running min-dist vs the tn new centers ----
        for (int tt = 0; tt < tn; ++tt) {
            const float cx = wcx[tt], cy = wcy[tt], cz = wcz[tt];
#pragma unroll
            for (int q = 0; q < WPT; ++q) {
                const float dx = __fsub_rn(px[q], cx);
                const float dy = __fsub_rn(py[q], cy);
                const float dz = __fsub_rn(pz[q], cz);
                const float s2 = __fmaf_rn(dz, dz,
                                 __fmaf_rn(dx, dx,
                                 __fmul_rn(dy, dy)));
                pd[q] = fminf(pd[q], s2);
            }
        }

        // ---- per-lane top-2 keys over its 8 points ----
        u64 k1 = 0, k2 = 0;
#pragma unroll
        for (int q = 0; q < WPT; ++q) {
            const u64 kk = ((u64)fbits(pd[q]) << 16)
                         | (u64)(0xFFFFu ^ (u32)(p0 + q * THREADS + t));
            if (kk > k1) { k2 = k1; k1 = kk; } else if (kk > k2) { k2 = kk; }
        }
        // ---- group top-2 butterfly (xor levels within GROUPL lanes) ----
#pragma unroll
        for (int m = 1; m <= GROUPL / 2; m <<= 1) {
            const u64 o1 = __shfl_xor(k1, m);
            const u64 o2 = __shfl_xor(k2, m);
            if (o1 > k1) { k2 = (k1 > o2) ? k1 : o2; k1 = o1; }
            else         { k2 = (k2 > o1) ? k2 : o1; }
        }

        u64* const bb = slots + ((size_t)(s & 1) * NBATCH + b) * POOLW;
        const u32 tag = (u32)s & 0xFFFFu;

        // ---- publish: first lane of each group stores its 2 tagged words ----
        if ((lane & (GROUPL - 1)) == 0) {
            const int g = wave * GPW + lane / GROUPL;   // group id in block
            __hip_atomic_store(&bb[j * (NWAVE * GPW * 2) + g * 2 + 0],
                               (k1 << 16) | tag,
                               __ATOMIC_RELAXED, __HIP_MEMORY_SCOPE_AGENT);
            __hip_atomic_store(&bb[j * (NWAVE * GPW * 2) + g * 2 + 1],
                               (k2 << 16) | tag,
                               __ATOMIC_RELAXED, __HIP_MEMORY_SCOPE_AGENT);
        }
        // waves 1..15 fall through to the loop-top barrier; wave 0 polls.

        if (wave == 0) {
            // ---- poll: WPL coalesced words/lane until all carry tag s ----
            u64 w[WPL]; int ok;
            do {
#pragma unroll
                for (int r = 0; r < WPL; ++r)
                    w[r] = __hip_atomic_load(&bb[lane + 64 * r],
                                             __ATOMIC_RELAXED, __HIP_MEMORY_SCOPE_AGENT);
                ok = 1;
#pragma unroll
                for (int r = 0; r < WPL; ++r)
                    ok &= ((u32)(w[r] & 0xFFFFull) == tag);
            } while (!__all(ok));

            // ---- unpack pool: split (val, inv-idx) + gather coords ----
            u32 pv[WPL], pi[WPL];
            float ex[WPL], ey[WPL], ez[WPL];
#pragma unroll
            for (int r = 0; r < WPL; ++r) {
                pv[r] = (u32)(w[r] >> 32);
                pi[r] = ((u32)w[r] >> 16) & 0xFFFFu;
                const int gi = (int)(0xFFFFu ^ pi[r]);   // global point idx
                ex[r] = base[(size_t)gi * 3 + 0];
                ey[r] = base[(size_t)gi * 3 + 1];
                ez[r] = base[(size_t)gi * 3 + 2];
            }

            // tau = max over group-SECOND entries (word idx = lane+64r, so
            // (idx&1)==(lane&1): odd lanes hold exactly the second entries).
            u32 tl = 0;
#pragma unroll
            for (int r = 0; r < WPL; ++r) tl = pv[r] > tl ? pv[r] : tl;
            tl = (lane & 1) ? tl : 0u;
            const u32 tauv = wave_max_u32(tl);

            // ---- pool-FPS: exact multi-step selection ----
            int tc = 0;
            while (1) {
                u32 lv = 0;
#pragma unroll
                for (int r = 0; r < WPL; ++r) lv = pv[r] > lv ? pv[r] : lv;
                const u32 vmax = wave_max_u32(lv);
                // step >=2 valid only if winner VALUE strictly beats tau
                if (tc > 0 && vmax <= tauv) break;

                // tie-break: smallest global idx == largest inv (sentinel +1)
                u32 ic = 0;
#pragma unroll
                for (int r = 0; r < WPL; ++r)
                    ic = (pv[r] == vmax && pi[r] + 1u > ic) ? pi[r] + 1u : ic;
                const u32 winv = wave_max_u32(ic) - 1u;

                // owner entry -> winner coords to all lanes
                float sx = 0.f, sy = 0.f, sz = 0.f; int mm = 0;
#pragma unroll
                for (int r = 0; r < WPL; ++r) {
                    const int m = (pv[r] == vmax) & (pi[r] == winv);
                    mm |= m;
                    sx = m ? ex[r] : sx;
                    sy = m ? ey[r] : sy;
                    sz = m ? ez[r] : sz;
                }
                const u64 bal = __ballot(mm);
                const int ol = (int)__ffsll((long long)bal) - 1;
                const float wx = __shfl(sx, ol);
                const float wy = __shfl(sy, ol);
                const float wz = __shfl(sz, ol);

                if (lane == 0) {
                    wcx[tc] = wx; wcy[tc] = wy; wcz[tc] = wz;
                    if (j == 0) {
                        float* o = out + ((size_t)b * MCENT + (C + tc)) * 3;
                        o[0] = wx; o[1] = wy; o[2] = wz;
                    }
                }
                ++tc;
                if (C + tc >= MCENT || tc >= TMAX) break;

                // min-update all entries vs winner (bit-exact chain);
                // winner's own entry sinks to 0 automatically
#pragma unroll
                for (int r = 0; r < WPL; ++r) {
                    const float dx = __fsub_rn(ex[r], wx);
                    const float dy = __fsub_rn(ey[r], wy);
                    const float dz = __fsub_rn(ez[r], wz);
                    const float s2 = __fmaf_rn(dz, dz,
                                     __fmaf_rn(dx, dx,
                                     __fmul_rn(dy, dy)));
                    pv[r] = fbits(fminf(bitsf(pv[r]), s2));
                }
            }
            if (lane == 0) wcnt = tc;
        }
    }
}

extern "C" void kernel_launch(void* const* d_in, const int* in_sizes, int n_in,
                              void* d_out, int out_size, void* d_ws, size_t ws_size,
                              hipStream_t stream) {
    const float* xyz = (const float*)d_in[0];
    float* out = (float*)d_out;
    u64* slots = (u64*)d_ws;

    // deep (half-wave) pool needs 2 parity x 32 batch x 512 words x 8 B
    const size_t need_deep = 2ull * NBATCH * (BPB * NWAVE * 2 * 2) * sizeof(u64);
    if (ws_size >= need_deep) {
        fps_kernel<2><<<dim3(NBATCH * BPB), dim3(THREADS), 0, stream>>>(xyz, out, slots);
    } else {
        // proven 128 KiB fallback (R2 protocol)
        fps_kernel<1><<<dim3(NBATCH * BPB), dim3(THREADS), 0, stream>>>(xyz, out, slots);
    }
}

// Round 5
// 2054.748 us; speedup vs baseline: 3.1303x; 1.0172x over previous
//
#include <hip/hip_runtime.h>
#include <stdint.h>

#define NBATCH 32
#define NPTS   65536
#define MCENT  2048
#define BPB    8                 // blocks per batch
#define THREADS 1024
#define CHUNK  (NPTS / BPB)      // 8192 points per block
#define WPT    (CHUNK / THREADS) // 8 points per thread
#define NWAVE  (THREADS / 64)    // 16 waves
#define GPW    2                 // groups (half-waves) per wave
#define NGRP   (NWAVE * GPW)     // 32 groups per block
#define TMAX   64                // max centers selected per sync round

typedef unsigned long long u64;
typedef uint32_t u32;

static __device__ __forceinline__ u32 fbits(float f) { union { float f; u32 u; } c; c.f = f; return c.u; }
static __device__ __forceinline__ float bitsf(u32 u) { union { u32 u; float f; } c; c.u = u; return c.f; }

// wave-wide max of nonneg u32 via DPP row reduce (proven R4);
// bound_ctrl=true -> invalid sources read 0 (identity for nonneg max).
static __device__ __forceinline__ u32 wave_max_u32(u32 v) {
#define STEP(CTRL) { const u32 o = (u32)__builtin_amdgcn_update_dpp(0, (int)v, CTRL, 0xF, 0xF, true); v = o > v ? o : v; }
    STEP(0x111) // row_shr:1
    STEP(0x112) // row_shr:2
    STEP(0x114) // row_shr:4
    STEP(0x118) // row_shr:8
    STEP(0x142) // row_bcast15
    STEP(0x143) // row_bcast31
#undef STEP
    return (u32)__builtin_amdgcn_readlane((int)v, 63);
}

// Multi-step FPS with a published candidate pool; one all-to-all sync
// amortizes over several exact FPS steps.
//
// TOPK = published entries per 256-pt group (half-wave). TOPK=2 is the
// proven R4 protocol (256 KiB ws). TOPK=3 lowers tau to the max of group
// THIRDS (first triple-collision order statistic ~3x deeper than first
// pair-collision) -> more accepted steps per sync; needs 384 KiB ws.
// Host gates on ws_size; fallback is bit-identical R4 semantics.
//
// Pool protocol (d_ws = 2 parity x NBATCH x POOLW u64 words):
//   word = val_bits[63:32] | (idx^0xFFFF)[31:16] | sync_tag[15:0]
//   key order (val desc, idx asc) == jnp.argmax first-occurrence semantics.
//   Tags: poison 0xAA.. -> 0xAAAA, zero -> 0; s in [1,2047] never aliases.
//   Parity reuse safe: a block overwrites parity-p words at round s+2 only
//   after observing all round-s+1 tags; a peer publishes s+1 only after its
//   round-s poll banked all round-s words in registers.
//
// Exactness (every block replicates the identical pool computation):
//   step 1: pool holds every group's max -> pool argmax == global argmax.
//   step t>=2: any point NOT in the pool is <= its group's published
//   TOPK-th value <= tau = max over groups of TOPK-th values (true dists
//   only decrease). Accept a winner iff its VALUE strictly > tau (hidden
//   points can then neither beat nor tie it); else bail and re-sync.
//   All distance math is the verified bit-exact chain: subs, then
//   fma(dz,dz, fma(dx,dx, mul(dy,dy))), chronological fminf order.

template<int TOPK>
__global__ __launch_bounds__(THREADS, 1) void fps_kernel(
    const float* __restrict__ xyz,      // [NBATCH, NPTS, 3] fp32
    float* __restrict__ out,            // [NBATCH, MCENT, 3] fp32
    u64* __restrict__ slots)
{
    constexpr int POOLW = BPB * NGRP * TOPK;   // words per batch per parity
    constexpr int WPL   = POOLW / 64;          // words per lane (wave 0)

    const int t = threadIdx.x;
    const int b = blockIdx.x >> 3;   // batch (proven mapping)
    const int j = blockIdx.x & 7;    // block-within-batch
    const float* base = xyz + (size_t)b * NPTS * 3;
    const int p0 = j * CHUNK;
    const int wave = t >> 6;
    const int lane = t & 63;

    // coords + running min-dist live in registers
    float px[WPT], py[WPT], pz[WPT], pd[WPT];
#pragma unroll
    for (int q = 0; q < WPT; ++q) {
        const int p = p0 + q * THREADS + t;
        px[q] = base[(size_t)p * 3 + 0];
        py[q] = base[(size_t)p * 3 + 1];
        pz[q] = base[(size_t)p * 3 + 2];
        pd[q] = 1e10f;
    }

    __shared__ float wcx[TMAX], wcy[TMAX], wcz[TMAX]; // winners of last round
    __shared__ int   wcnt;

    if (t == 0) {
        const float cx = base[0], cy = base[1], cz = base[2];
        wcx[0] = cx; wcy[0] = cy; wcz[0] = cz; wcnt = 1;
        if (j == 0) {
            float* o = out + (size_t)b * MCENT * 3;
            o[0] = cx; o[1] = cy; o[2] = cz;
        }
    }

    int C = 0;  // centers accounted (uniform across all blocks)
    for (int s = 1; ; ++s) {
        __syncthreads();                 // wcnt / wc* of previous round valid
        const int tn = wcnt;
        C += tn;
        if (C >= MCENT) break;

        // ---- Phase A: update running min-dist vs the tn new centers ----
        for (int tt = 0; tt < tn; ++tt) {
            const float cx = wcx[tt], cy = wcy[tt], cz = wcz[tt];
#pragma unroll
            for (int q = 0; q < WPT; ++q) {
                const float dx = __fsub_rn(px[q], cx);
                const float dy = __fsub_rn(py[q], cy);
                const float dz = __fsub_rn(pz[q], cz);
                const float s2 = __fmaf_rn(dz, dz,
                                 __fmaf_rn(dx, dx,
                                 __fmul_rn(dy, dy)));
                pd[q] = fminf(pd[q], s2);
            }
        }

        // ---- per-lane top-TOPK keys over its 8 points (sorted insert) ----
        u64 k1 = 0, k2 = 0, k3 = 0;
#pragma unroll
        for (int q = 0; q < WPT; ++q) {
            const u64 kk = ((u64)fbits(pd[q]) << 16)
                         | (u64)(0xFFFFu ^ (u32)(p0 + q * THREADS + t));
            if (kk > k1)      { k3 = k2; k2 = k1; k1 = kk; }
            else if (kk > k2) { k3 = k2; k2 = kk; }
            else if (kk > k3) { k3 = kk; }
        }
        // ---- half-wave top-TOPK butterfly (5 xor levels, 32 lanes) ----
#pragma unroll
        for (int m = 1; m <= 16; m <<= 1) {
            const u64 o1 = __shfl_xor(k1, m);
            const u64 o2 = __shfl_xor(k2, m);
            if constexpr (TOPK == 2) {
                if (o1 > k1) { k2 = (k1 > o2) ? k1 : o2; k1 = o1; }
                else         { k2 = (k2 > o1) ? k2 : o1; }
            } else {
                const u64 o3 = __shfl_xor(k3, m);
                // merge sorted triples (k1>=k2>=k3), (o1>=o2>=o3) -> top-3
                u64 m1, m2, m3;
                if (o1 > k1) {
                    m1 = o1;
                    if (o2 > k1) { m2 = o2; m3 = (o3 > k1) ? o3 : k1; }
                    else         { m2 = k1; m3 = (o2 > k2) ? o2 : k2; }
                } else {
                    m1 = k1;
                    if (o1 > k2) { m2 = o1; m3 = (o2 > k2) ? o2 : k2; }
                    else         { m2 = k2; m3 = (o1 > k3) ? o1 : k3; }
                }
                k1 = m1; k2 = m2; k3 = m3;
            }
        }

        u64* const bb = slots + ((size_t)(s & 1) * NBATCH + b) * POOLW;
        const u32 tag = (u32)s & 0xFFFFu;

        // ---- publish: first lane of each half-wave stores TOPK words ----
        if ((lane & 31) == 0) {
            const int g = wave * GPW + (lane >> 5);     // group id 0..31
            u64* const gw = &bb[j * (NGRP * TOPK) + g * TOPK];
            __hip_atomic_store(&gw[0], (k1 << 16) | tag,
                               __ATOMIC_RELAXED, __HIP_MEMORY_SCOPE_AGENT);
            __hip_atomic_store(&gw[1], (k2 << 16) | tag,
                               __ATOMIC_RELAXED, __HIP_MEMORY_SCOPE_AGENT);
            if constexpr (TOPK == 3)
                __hip_atomic_store(&gw[2], (k3 << 16) | tag,
                                   __ATOMIC_RELAXED, __HIP_MEMORY_SCOPE_AGENT);
        }
        // waves 1..15 fall through to the loop-top barrier; wave 0 polls.

        if (wave == 0) {
            // ---- poll: WPL coalesced words/lane until all carry tag s ----
            u64 w[WPL]; int ok;
            do {
#pragma unroll
                for (int r = 0; r < WPL; ++r)
                    w[r] = __hip_atomic_load(&bb[lane + 64 * r],
                                             __ATOMIC_RELAXED, __HIP_MEMORY_SCOPE_AGENT);
                ok = 1;
#pragma unroll
                for (int r = 0; r < WPL; ++r)
                    ok &= ((u32)(w[r] & 0xFFFFull) == tag);
            } while (!__all(ok));

            // ---- unpack pool: split (val, inv-idx) + gather coords ----
            u32 pv[WPL], pi[WPL];
            float ex[WPL], ey[WPL], ez[WPL];
#pragma unroll
            for (int r = 0; r < WPL; ++r) {
                pv[r] = (u32)(w[r] >> 32);
                pi[r] = ((u32)w[r] >> 16) & 0xFFFFu;
                const int gi = (int)(0xFFFFu ^ pi[r]);   // global point idx
                ex[r] = base[(size_t)gi * 3 + 0];
                ey[r] = base[(size_t)gi * 3 + 1];
                ez[r] = base[(size_t)gi * 3 + 2];
            }

            // tau = max over group-LAST (TOPK-th) entries. Word index is
            // lane + 64*r -> rank = (lane%TOPK + (64%TOPK)*r) % TOPK.
            u32 tl = 0;
#pragma unroll
            for (int r = 0; r < WPL; ++r) {
                const int rank = ((lane % TOPK) + (64 % TOPK) * r) % TOPK;
                if (rank == TOPK - 1) tl = pv[r] > tl ? pv[r] : tl;
            }
            const u32 tauv = wave_max_u32(tl);

            // ---- pool-FPS: exact multi-step selection ----
            int tc = 0;
            while (1) {
                u32 lv = 0;
#pragma unroll
                for (int r = 0; r < WPL; ++r) lv = pv[r] > lv ? pv[r] : lv;
                const u32 vmax = wave_max_u32(lv);
                // step >=2 valid only if winner VALUE strictly beats tau
                if (tc > 0 && vmax <= tauv) break;

                // per-lane best inv among entries matching vmax (0 = none)
                u32 ic = 0;
#pragma unroll
                for (int r = 0; r < WPL; ++r)
                    ic = (pv[r] == vmax && pi[r] + 1u > ic) ? pi[r] + 1u : ic;
                const u64 bal = __ballot(ic != 0);
                u32 winv; int ol;
                if (__popcll(bal) == 1) {
                    // single owner lane: local tie-break already in ic
                    ol = (int)__ffsll((long long)bal) - 1;
                    winv = __shfl(ic, ol) - 1u;
                } else {
                    // exact cross-lane tie-break: smallest global idx
                    winv = wave_max_u32(ic) - 1u;
                    int m = 0;
#pragma unroll
                    for (int r = 0; r < WPL; ++r)
                        m |= (pv[r] == vmax) & (pi[r] == winv);
                    ol = (int)__ffsll((long long)__ballot(m)) - 1;
                }

                // owner entry -> winner coords to all lanes
                float sx = 0.f, sy = 0.f, sz = 0.f;
#pragma unroll
                for (int r = 0; r < WPL; ++r) {
                    const int m = (pv[r] == vmax) & (pi[r] == winv);
                    sx = m ? ex[r] : sx;
                    sy = m ? ey[r] : sy;
                    sz = m ? ez[r] : sz;
                }
                const float wx = __shfl(sx, ol);
                const float wy = __shfl(sy, ol);
                const float wz = __shfl(sz, ol);

                if (lane == 0) {
                    wcx[tc] = wx; wcy[tc] = wy; wcz[tc] = wz;
                    if (j == 0) {
                        float* o = out + ((size_t)b * MCENT + (C + tc)) * 3;
                        o[0] = wx; o[1] = wy; o[2] = wz;
                    }
                }
                ++tc;
                if (C + tc >= MCENT || tc >= TMAX) break;

                // min-update all entries vs winner (bit-exact chain);
                // winner's own entry sinks to 0 automatically
#pragma unroll
                for (int r = 0; r < WPL; ++r) {
                    const float dx = __fsub_rn(ex[r], wx);
                    const float dy = __fsub_rn(ey[r], wy);
                    const float dz = __fsub_rn(ez[r], wz);
                    const float s2 = __fmaf_rn(dz, dz,
                                     __fmaf_rn(dx, dx,
                                     __fmul_rn(dy, dy)));
                    pv[r] = fbits(fminf(bitsf(pv[r]), s2));
                }
            }
            if (lane == 0) wcnt = tc;
        }
    }
}

extern "C" void kernel_launch(void* const* d_in, const int* in_sizes, int n_in,
                              void* d_out, int out_size, void* d_ws, size_t ws_size,
                              hipStream_t stream) {
    const float* xyz = (const float*)d_in[0];
    float* out = (float*)d_out;
    u64* slots = (u64*)d_ws;

    // top-3 pool needs 2 parity x 32 batch x 768 words x 8 B = 384 KiB
    const size_t need3 = 2ull * NBATCH * (BPB * NGRP * 3) * sizeof(u64);
    if (ws_size >= need3) {
        fps_kernel<3><<<dim3(NBATCH * BPB), dim3(THREADS), 0, stream>>>(xyz, out, slots);
    } else {
        // proven R4 deep fallback (256 KiB)
        fps_kernel<2><<<dim3(NBATCH * BPB), dim3(THREADS), 0, stream>>>(xyz, out, slots);
    }
}